// Round 1
// baseline (216.961 us; speedup 1.0000x reference)
//
#include <hip/hip_runtime.h>

// Problem constants (fixed by the reference).
#define T_LEN 4096
#define B_SZ  2
#define H_SZ  2048
#define NM    8            // N2 complex modes
#define BH    (B_SZ * H_SZ)

// ---------------------------------------------------------------------------
// S4D via chunked linear recurrence (exact equivalent of the FFT conv):
//   S_n(t) = w_n * S_n(t-1) + x(t),  w_n = exp(dt*A_n)
//   out(t) = 2*Re( sum_n Cd_n * S_n(t) ) + D*x(t),  Cd = C*(w-1)/A
// k1: per-(chunk,b,h) local scan -> end states (no carry) into d_ws
// k2: per-(b,h,n) sequential scan across chunks -> carry-in per chunk
// k3: per-(chunk,b,h) re-scan from carry-in -> output
// ---------------------------------------------------------------------------

__device__ __forceinline__ void load_w(const float* __restrict__ log_dt,
                                       const float* __restrict__ Arl,
                                       const float* __restrict__ Aimp,
                                       int h, float* wr, float* wi,
                                       float* Are_o, float* Aim_o, float* dt_o) {
    float dt = __expf(log_dt[h]);
    *dt_o = dt;
#pragma unroll
    for (int n = 0; n < NM; ++n) {
        float Are = -__expf(Arl[h * NM + n]);
        float Aim = Aimp[h * NM + n];
        float er  = __expf(Are * dt);
        float ang = Aim * dt;
        wr[n] = er * cosf(ang);
        wi[n] = er * sinf(ang);
        Are_o[n] = Are;
        Aim_o[n] = Aim;
    }
}

__global__ void __launch_bounds__(256)
k1_chunk_end(const float* __restrict__ x,
             const float* __restrict__ log_dt,
             const float* __restrict__ Arl,
             const float* __restrict__ Aimp,
             float2* __restrict__ states,
             int Lc, int C) {
    int g = blockIdx.x * blockDim.x + threadIdx.x;
    if (g >= C * BH) return;
    int h = g % H_SZ;
    int b = (g / H_SZ) % B_SZ;
    int c = g / BH;

    float wr[NM], wi[NM], Are[NM], Aim[NM], dt;
    load_w(log_dt, Arl, Aimp, h, wr, wi, Are, Aim, &dt);

    float sr[NM], si[NM];
#pragma unroll
    for (int n = 0; n < NM; ++n) { sr[n] = 0.f; si[n] = 0.f; }

    const float* xp = x + (size_t)(c * Lc) * BH + b * H_SZ + h;
    for (int t = 0; t < Lc; ++t) {
        float xv = xp[(size_t)t * BH];
#pragma unroll
        for (int n = 0; n < NM; ++n) {
            float nsr = fmaf(wr[n], sr[n], fmaf(-wi[n], si[n], xv));
            float nsi = fmaf(wr[n], si[n], wi[n] * sr[n]);
            sr[n] = nsr; si[n] = nsi;
        }
    }
    float2* st = states + (size_t)((c * B_SZ + b) * H_SZ + h) * NM;
#pragma unroll
    for (int n = 0; n < NM; ++n) st[n] = make_float2(sr[n], si[n]);
}

__global__ void __launch_bounds__(256)
k2_carry_scan(const float* __restrict__ log_dt,
              const float* __restrict__ Arl,
              const float* __restrict__ Aimp,
              float2* __restrict__ states,
              int Lc, int C) {
    int g = blockIdx.x * blockDim.x + threadIdx.x;
    if (g >= BH * NM) return;
    int n = g % NM;
    int h = (g / NM) % H_SZ;
    int b = g / (NM * H_SZ);

    float dt  = __expf(log_dt[h]);
    float Are = -__expf(Arl[h * NM + n]);
    float Aim = Aimp[h * NM + n];
    // w^Lc = exp(dt*A*Lc)
    float er  = __expf(Are * dt * (float)Lc);
    float ang = Aim * dt * (float)Lc;
    float wr = er * cosf(ang), wi = er * sinf(ang);

    float cr = 0.f, ci = 0.f;
    for (int c = 0; c < C; ++c) {
        size_t idx = (size_t)((c * B_SZ + b) * H_SZ + h) * NM + n;
        float2 tmp = states[idx];
        states[idx] = make_float2(cr, ci);   // exclusive: carry INTO chunk c
        float ncr = fmaf(wr, cr, fmaf(-wi, ci, tmp.x));
        float nci = fmaf(wr, ci, fmaf(wi, cr, tmp.y));
        cr = ncr; ci = nci;
    }
}

__global__ void __launch_bounds__(256)
k3_output(const float* __restrict__ x,
          const float* __restrict__ Dp,
          const float* __restrict__ log_dt,
          const float* __restrict__ Arl,
          const float* __restrict__ Aimp,
          const float* __restrict__ Crep,
          const float* __restrict__ Cimp,
          const float2* __restrict__ states,
          float* __restrict__ out,
          int Lc, int C) {
    int g = blockIdx.x * blockDim.x + threadIdx.x;
    if (g >= C * BH) return;
    int h = g % H_SZ;
    int b = (g / H_SZ) % B_SZ;
    int c = g / BH;

    float wr[NM], wi[NM], Are[NM], Aim[NM], dt;
    load_w(log_dt, Arl, Aimp, h, wr, wi, Are, Aim, &dt);

    // Cd = (Cre + i*Cim) * (w - 1) / A   (divide via conj(A)/|A|^2)
    float cdr[NM], cdi[NM];
#pragma unroll
    for (int n = 0; n < NM; ++n) {
        float den = Are[n] * Are[n] + Aim[n] * Aim[n];
        float inv = 1.0f / den;
        float tr = ((wr[n] - 1.f) * Are[n] + wi[n] * Aim[n]) * inv;
        float ti = (wi[n] * Are[n] - (wr[n] - 1.f) * Aim[n]) * inv;
        float Cre = Crep[h * NM + n], Cim = Cimp[h * NM + n];
        cdr[n] = Cre * tr - Cim * ti;
        cdi[n] = Cre * ti + Cim * tr;
    }

    // carry-in state
    const float2* st = states + (size_t)((c * B_SZ + b) * H_SZ + h) * NM;
    float sr[NM], si[NM];
#pragma unroll
    for (int n = 0; n < NM; ++n) { float2 v = st[n]; sr[n] = v.x; si[n] = v.y; }

    float Dv = Dp[h];
    const float* xp = x + (size_t)(c * Lc) * BH + b * H_SZ + h;
    float* op = out + (size_t)(c * Lc) * BH + b * H_SZ + h;
    for (int t = 0; t < Lc; ++t) {
        float xv = xp[(size_t)t * BH];
        float y = 0.f;
#pragma unroll
        for (int n = 0; n < NM; ++n) {
            float nsr = fmaf(wr[n], sr[n], fmaf(-wi[n], si[n], xv));
            float nsi = fmaf(wr[n], si[n], wi[n] * sr[n]);
            sr[n] = nsr; si[n] = nsi;
            y = fmaf(cdr[n], sr[n], y);
            y = fmaf(-cdi[n], si[n], y);
        }
        op[(size_t)t * BH] = fmaf(Dv, xv, 2.0f * y);
    }
}

extern "C" void kernel_launch(void* const* d_in, const int* in_sizes, int n_in,
                              void* d_out, int out_size, void* d_ws, size_t ws_size,
                              hipStream_t stream) {
    const float* x      = (const float*)d_in[0];
    const float* Dp     = (const float*)d_in[1];
    const float* log_dt = (const float*)d_in[2];
    const float* Arl    = (const float*)d_in[3];
    const float* Aimp   = (const float*)d_in[4];
    const float* Cre    = (const float*)d_in[5];
    const float* Cim    = (const float*)d_in[6];
    float* out = (float*)d_out;
    float2* states = (float2*)d_ws;

    // Pick the largest power-of-two chunk count whose state array fits in ws.
    int C = 64;
    while (C > 1 && (size_t)C * BH * NM * sizeof(float2) > ws_size) C >>= 1;
    int Lc = T_LEN / C;

    int total = C * BH;
    int blocks = (total + 255) / 256;
    k1_chunk_end<<<blocks, 256, 0, stream>>>(x, log_dt, Arl, Aimp, states, Lc, C);

    int total2 = BH * NM;
    int blocks2 = (total2 + 255) / 256;
    k2_carry_scan<<<blocks2, 256, 0, stream>>>(log_dt, Arl, Aimp, states, Lc, C);

    k3_output<<<blocks, 256, 0, stream>>>(x, Dp, log_dt, Arl, Aimp, Cre, Cim,
                                          states, out, Lc, C);
}